// Round 1
// baseline (1191.930 us; speedup 1.0000x reference)
//
#include <hip/hip_runtime.h>

// GroupGSDConv: per-output-channel dilated 3x3 conv, fp32.
// B=16, C=64 in/out, H=W=128, dilation d = offsets[oc] in [1,6], padding=d.
//
// Strategy (round 1, fp32 VALU baseline):
//  - setup kernel groups output channels by dilation into tiles of 8 (uniform
//    d per block) -> descriptors in d_ws. Max tiles = 13 (sum ceil(G_d/8)).
//  - main kernel: block = 8 output channels x (32y x 64x) spatial tile of one
//    batch. Thread = 8 oc x 8 px register tile (64 acc VGPRs): 64 FMAs per
//    8 LDS input reads + 8 scalar weight loads -> FMA-bound, not LDS-bound.
//  - input channel tile staged to LDS with halo d, leading stride padded to
//    odd (bank-conflict free at 2-way).

#define B_ 16
#define C_ 64
#define HW_ 128
#define TY 32
#define TX 64
#define MAX_TILES 13

__global__ __launch_bounds__(64) void gsd_setup(const int* __restrict__ offsets,
                                                int* __restrict__ desc) {
  __shared__ int offs[C_];
  const int t = threadIdx.x;
  offs[t] = offsets[t];
  __syncthreads();
  if (t == 0) {
    int nt = 0;
    for (int d = 1; d <= 6; ++d) {
      int chans[C_];
      int cnt = 0;
      for (int c = 0; c < C_; ++c)
        if (offs[c] == d) chans[cnt++] = c;
      for (int base = 0; base < cnt; base += 8) {
        desc[nt * 9] = d;
        for (int j = 0; j < 8; ++j)
          desc[nt * 9 + 1 + j] = (base + j < cnt) ? chans[base + j] : -1;
        ++nt;
      }
    }
    for (; nt < MAX_TILES; ++nt) desc[nt * 9] = 0;  // inactive tile marker
  }
}

__global__ __launch_bounds__(256) void gsd_conv(const float* __restrict__ x,
                                                const float* __restrict__ w,
                                                const int* __restrict__ desc,
                                                float* __restrict__ out) {
  const int tid = threadIdx.x;
  const int tdesc = blockIdx.y;

  // Block-uniform dilation + channel list (forced to SGPRs).
  const int d = __builtin_amdgcn_readfirstlane(desc[tdesc * 9]);
  if (d == 0) return;  // padded tile slot, uniform exit before any barrier

  int c[8];
  const float* wrow[8];
#pragma unroll
  for (int o = 0; o < 8; ++o) {
    c[o] = __builtin_amdgcn_readfirstlane(desc[tdesc * 9 + 1 + o]);
    const int cs = c[o] < 0 ? 0 : c[o];
    wrow[o] = w + cs * (C_ * 9);
  }

  const int sb = blockIdx.x;  // b * 8 + spatial tile
  const int b = sb >> 3;
  const int st = sb & 7;
  const int y0 = (st >> 1) * TY;  // 4 tiles in y
  const int x0 = (st & 1) * TX;   // 2 tiles in x

  const int tx = tid & 7;   // 8 px-groups along x (8 px each)
  const int ty = tid >> 3;  // 32 rows
  const int sx = tid & 63;  // staging lane mapping (64-contiguous)
  const int sy = tid >> 6;

  const int ext_x = TX + 2 * d;
  const int ext_y = TY + 2 * d;
  const int ldw = ext_x + 1;  // odd stride -> <=2-way LDS bank aliasing (free)

  __shared__ float tile[(TY + 12) * (TX + 13)];  // worst case 44*77 floats

  float acc[8][8];
#pragma unroll
  for (int o = 0; o < 8; ++o)
#pragma unroll
    for (int i = 0; i < 8; ++i) acc[o][i] = 0.f;

  const float* xb = x + (size_t)b * (C_ * HW_ * HW_);

  for (int ic = 0; ic < C_; ++ic) {
    // ---- stage input channel tile (halo d, zero-padded) ----
    const float* xsrc = xb + ic * (HW_ * HW_);
    for (int r = sy; r < ext_y; r += 4) {
      const int gy = y0 - d + r;
      const bool rowok = (unsigned)gy < (unsigned)HW_;
      float* drow = &tile[r * ldw];
      for (int cl = sx; cl < ext_x; cl += 64) {
        const int gx = x0 - d + cl;
        float v = 0.f;
        if (rowok && (unsigned)gx < (unsigned)HW_) v = xsrc[gy * HW_ + gx];
        drow[cl] = v;
      }
    }
    __syncthreads();

    // ---- compute: 9 taps, 8 oc x 8 px outer product ----
    const float* lbase = &tile[ty * ldw + tx * 8];
#pragma unroll
    for (int ky = 0; ky < 3; ++ky) {
#pragma unroll
      for (int kx = 0; kx < 3; ++kx) {
        const float* p = lbase + (ky * d) * ldw + kx * d;
        float in8[8];
#pragma unroll
        for (int i = 0; i < 8; ++i) in8[i] = p[i];
        float wv[8];
#pragma unroll
        for (int o = 0; o < 8; ++o) wv[o] = wrow[o][ic * 9 + ky * 3 + kx];
#pragma unroll
        for (int o = 0; o < 8; ++o)
#pragma unroll
          for (int i = 0; i < 8; ++i) acc[o][i] += wv[o] * in8[i];
      }
    }
    __syncthreads();
  }

  // ---- store 8 oc x 8 px as 2x float4 per oc ----
  const int gy = y0 + ty;
  const int gx = x0 + tx * 8;
#pragma unroll
  for (int o = 0; o < 8; ++o) {
    if (c[o] >= 0) {
      float* op = out + (((size_t)(b * C_ + c[o]) * HW_ + gy) * HW_ + gx);
      float4 v0 = {acc[o][0], acc[o][1], acc[o][2], acc[o][3]};
      float4 v1 = {acc[o][4], acc[o][5], acc[o][6], acc[o][7]};
      reinterpret_cast<float4*>(op)[0] = v0;
      reinterpret_cast<float4*>(op)[1] = v1;
    }
  }
}

extern "C" void kernel_launch(void* const* d_in, const int* in_sizes, int n_in,
                              void* d_out, int out_size, void* d_ws, size_t ws_size,
                              hipStream_t stream) {
  const float* x = (const float*)d_in[0];       // [16,64,128,128] fp32
  const float* w = (const float*)d_in[1];       // [64,64,3,3] fp32
  const int* offsets = (const int*)d_in[2];     // [64] int32 in [1,6]
  float* out = (float*)d_out;                   // [16,64,128,128] fp32
  int* desc = (int*)d_ws;                       // 13 tiles x 9 ints

  gsd_setup<<<1, 64, 0, stream>>>(offsets, desc);

  dim3 grid(B_ * (HW_ / TY) * (HW_ / TX), MAX_TILES);  // (128, 13)
  gsd_conv<<<grid, 256, 0, stream>>>(x, w, desc, out);
}

// Round 2
// 448.600 us; speedup vs baseline: 2.6570x; 2.6570x over previous
//
#include <hip/hip_runtime.h>

// GroupGSDConv round 2: bf16 MFMA implicit GEMM.
// Conv = 9 per-tap GEMMs D[oc][px] += W[oc][ic] * X[ic][px_shifted].
// mfma_f32_16x16x32_bf16: A = weights (M=16 oc, uniform dilation per desc
// tile), B = pixels (N=16 x-consecutive), K = 32 ic per step (2 steps).
// A-frags prepacked in ws (lane layout m=lane&15, k=(lane>>4)*8+j) -> 72 VGPR.
// Input staged to LDS channel-last bf16 [pix][32ic]: pixel stride 16 dwords
// (aligned ds_read_b128, balanced banks), 16B-chunk XOR swizzle for writes.

#define HW_ 128
#define C_ 64
#define B_ 16
#define MAX_DESC 10
#define WS_WPACK_OFF 1024

typedef __attribute__((ext_vector_type(8))) short short8;
typedef __attribute__((ext_vector_type(4))) float floatx4;

__device__ __forceinline__ unsigned bf16rne(float f) {
  unsigned u = __float_as_uint(f);
  return (u + 0x7FFFu + ((u >> 16) & 1u)) >> 16;  // round-nearest-even
}

__global__ __launch_bounds__(256) void gsd_setup(
    const int* __restrict__ offsets, const float* __restrict__ w,
    int* __restrict__ desc, uint4* __restrict__ wpack) {
  __shared__ int sdesc[MAX_DESC * 17];
  const int tid = threadIdx.x;
  if (tid == 0) {
    int offs[C_];
    for (int c = 0; c < C_; ++c) offs[c] = offsets[c];
    int nt = 0;
    for (int d = 1; d <= 6; ++d) {
      int chans[C_];
      int cnt = 0;
      for (int c = 0; c < C_; ++c)
        if (offs[c] == d) chans[cnt++] = c;
      for (int base = 0; base < cnt; base += 16) {
        sdesc[nt * 17] = d;
        for (int j = 0; j < 16; ++j)
          sdesc[nt * 17 + 1 + j] = (base + j < cnt) ? chans[base + j] : -1;
        ++nt;
      }
    }
    for (; nt < MAX_DESC; ++nt) {
      sdesc[nt * 17] = 0;
      for (int j = 0; j < 16; ++j) sdesc[nt * 17 + 1 + j] = -1;
    }
  }
  __syncthreads();
  if (tid < MAX_DESC * 17) desc[tid] = sdesc[tid];

  // Pack weight A-fragments: wpack[((dsc*2+h)*9+t)*64+lane] = 8 bf16,
  // element j = W[oc=c[lane&15]][ic=h*32+(lane>>4)*8+j][tap t].
  for (int i = tid; i < MAX_DESC * 2 * 9 * 64; i += 256) {
    const int dsc = i / 1152, r1 = i % 1152;
    const int h = r1 / 576;
    const int r2 = r1 % 576;
    const int t = r2 >> 6;
    const int lane = r2 & 63;
    const int m = lane & 15, q = lane >> 4;
    const int oc = sdesc[dsc * 17 + 1 + m];
    unsigned ww[4];
    for (int jj = 0; jj < 4; ++jj) {
      float v0 = 0.f, v1 = 0.f;
      if (oc >= 0) {
        const int ic0 = h * 32 + q * 8 + jj * 2;
        v0 = w[(oc * C_ + ic0) * 9 + t];
        v1 = w[(oc * C_ + ic0 + 1) * 9 + t];
      }
      ww[jj] = bf16rne(v0) | (bf16rne(v1) << 16);
    }
    wpack[i] = make_uint4(ww[0], ww[1], ww[2], ww[3]);
  }
}

__global__ __launch_bounds__(256, 2) void gsd_conv(
    const float* __restrict__ x, const int* __restrict__ desc,
    const uint4* __restrict__ wpack, float* __restrict__ out) {
  const int tid = threadIdx.x;
  const int dsc = blockIdx.y;
  const int d = __builtin_amdgcn_readfirstlane(desc[dsc * 17]);
  if (d == 0) return;  // inactive desc slot: uniform exit before barriers

  const int gxid = blockIdx.x;
  const int b = gxid >> 5;
  const int yt = (gxid >> 3) & 3;
  const int xt = gxid & 7;
  const int y0 = yt * 32, x0 = xt * 16;

  const int lane = tid & 63;
  const int n = lane & 15;   // B-frag pixel / D col
  const int q = lane >> 4;   // K-chunk group / D row group
  const int wv = tid >> 6;   // wave id: owns output rows wv*8..wv*8+7

  const int ex = 16 + 2 * d;  // staged tile width  (<=28)
  const int ey = 32 + 2 * d;  // staged tile height (<=44)

  __shared__ unsigned ldsbuf[44 * 28 * 16];  // 78848 B -> 2 blocks/CU

  // ---- preload all 18 weight A-fragments (coalesced, L2-hot) ----
  short8 wf[2][9];
#pragma unroll
  for (int h = 0; h < 2; ++h)
#pragma unroll
    for (int t = 0; t < 9; ++t) {
      uint4 u = wpack[((dsc * 2 + h) * 9 + t) * 64 + lane];
      wf[h][t] = __builtin_bit_cast(short8, u);
    }

  floatx4 acc[8];
#pragma unroll
  for (int rr = 0; rr < 8; ++rr) acc[rr] = (floatx4){0.f, 0.f, 0.f, 0.f};

  // staging mapping: 32 lanes of x, 8 ic-quads (4 consecutive ic each)
  const int slx = tid & 31;
  const int sicq = tid >> 5;

  const float* xb = x + (size_t)b * (C_ * HW_ * HW_);

  for (int ks = 0; ks < 2; ++ks) {
    // ---- stage 32 input channels, fp32 -> bf16, channel-last ----
    const float* xp = xb + (size_t)(ks * 32 + sicq * 4) * (HW_ * HW_);
    const int gx = x0 - d + slx;
    const int gxc = gx < 0 ? 0 : (gx > 127 ? 127 : gx);
    const bool xok = (slx < ex) & ((unsigned)gx < 128u);
    for (int yy = 0; yy < ey; ++yy) {
      const int gy = y0 - d + yy;
      const int gyc = gy < 0 ? 0 : (gy > 127 ? 127 : gy);
      const bool ok = xok & ((unsigned)gy < 128u);
      const float* p = xp + gyc * HW_ + gxc;
      float v0 = p[0];
      float v1 = p[HW_ * HW_];
      float v2 = p[2 * HW_ * HW_];
      float v3 = p[3 * HW_ * HW_];
      if (!ok) { v0 = v1 = v2 = v3 = 0.f; }
      const unsigned lo = bf16rne(v0) | (bf16rne(v1) << 16);
      const unsigned hi = bf16rne(v2) | (bf16rne(v3) << 16);
      if (slx < ex) {
        const int pix = yy * ex + slx;
        const int chunk = (sicq >> 1) ^ ((pix >> 2) & 3);  // XOR swizzle
        const int dws = pix * 16 + chunk * 4 + (sicq & 1) * 2;
        *reinterpret_cast<uint2*>(&ldsbuf[dws]) = make_uint2(lo, hi);
      }
    }
    __syncthreads();

    // ---- 9 taps x 8 rows: ds_read_b128 B-frag + MFMA ----
#pragma unroll
    for (int t = 0; t < 9; ++t) {
      const int ky = t / 3, kx = t % 3;
#pragma unroll
      for (int rr = 0; rr < 8; ++rr) {
        const int r = wv * 8 + rr;
        const int pix = (r + ky * d) * ex + kx * d + n;
        const int chunk = q ^ ((pix >> 2) & 3);
        const int dws = pix * 16 + chunk * 4;
        const short8 bfrag =
            *reinterpret_cast<const short8*>(&ldsbuf[dws]);
        acc[rr] = __builtin_amdgcn_mfma_f32_16x16x32_bf16(wf[ks][t], bfrag,
                                                          acc[rr], 0, 0, 0);
      }
    }
    __syncthreads();
  }

  // ---- store: D[row=q*4+reg -> oc][col=n -> x], coalesced 16-lane runs ----
  int cid[4];
#pragma unroll
  for (int reg = 0; reg < 4; ++reg) cid[reg] = desc[dsc * 17 + 1 + q * 4 + reg];
#pragma unroll
  for (int rr = 0; rr < 8; ++rr) {
    const int y = y0 + wv * 8 + rr;
#pragma unroll
    for (int reg = 0; reg < 4; ++reg) {
      if (cid[reg] >= 0) {
        out[((size_t)(b * C_ + cid[reg]) * HW_ + y) * HW_ + x0 + n] =
            acc[rr][reg];
      }
    }
  }
}

extern "C" void kernel_launch(void* const* d_in, const int* in_sizes, int n_in,
                              void* d_out, int out_size, void* d_ws, size_t ws_size,
                              hipStream_t stream) {
  const float* x = (const float*)d_in[0];    // [16,64,128,128] fp32
  const float* w = (const float*)d_in[1];    // [64,64,3,3] fp32
  const int* offsets = (const int*)d_in[2];  // [64] int32 in [1,6]
  float* out = (float*)d_out;                // [16,64,128,128] fp32

  int* desc = (int*)d_ws;                                      // 10 x 17 ints
  uint4* wpack = (uint4*)((char*)d_ws + WS_WPACK_OFF);         // 184320 B

  gsd_setup<<<1, 256, 0, stream>>>(offsets, w, desc, wpack);

  dim3 grid(B_ * 4 * 8, MAX_DESC);  // (512, 10): b x ytile x xtile, desc
  gsd_conv<<<grid, 256, 0, stream>>>(x, desc, wpack, out);
}

// Round 3
// 244.156 us; speedup vs baseline: 4.8818x; 1.8374x over previous
//
#include <hip/hip_runtime.h>

// GroupGSDConv round 3: single-pass bf16 MFMA implicit GEMM.
// One block per spatial tile (32y x 16x) computes ALL 64 output channels:
//  - channels sorted by dilation (perm); 4 "octiles" of 16 sorted channels.
//  - octile with mixed dilations -> <=6 work items (octile, d); A-frag rows
//    of other dilations are zero-masked at pack time (sorted => total <= 9).
//  - acc[4][8] float4 = 128 VGPR, persistent across both 32-ic K-halves.
//  - input staged once per K-half with fixed halo 6 (ex=28, ey=44 compile
//    time), channel-last bf16 [pix][32ic], 16-dw pixel stride, XOR chunk
//    swizzle -> aligned ds_read_b128, ~conflict-free.
// Fetch = 512 * 44*28*64*4B = 161 MB (vs 921 MB in R2's per-desc grid).

#define HW_ 128
#define C_ 64
#define B_ 16
#define EX 28
#define EY 44
#define MAX_ITEMS 12
#define WS_WPACK_OFF 1024

// sdesc layout (ints):
//  [0..63]      perm (sorted-by-dilation output channel ids)
//  [64+t]       cnt[t]  (work items in octile t, t<4)
//  [68+t*6+s]   dilation of item (t,s)
//  [92+t*6+s]   wpack item index of item (t,s)

typedef __attribute__((ext_vector_type(8))) short short8;
typedef __attribute__((ext_vector_type(4))) float floatx4;

__device__ __forceinline__ unsigned bf16rne(float f) {
  unsigned u = __float_as_uint(f);
  return (u + 0x7FFFu + ((u >> 16) & 1u)) >> 16;  // round-nearest-even
}

__global__ __launch_bounds__(256) void gsd_setup(
    const int* __restrict__ offsets, const float* __restrict__ w,
    int* __restrict__ desc, uint4* __restrict__ wpack) {
  __shared__ int sd[128];
  __shared__ int soffs[C_];
  const int tid = threadIdx.x;
  if (tid < C_) soffs[tid] = offsets[tid];
  __syncthreads();
  if (tid == 0) {
    int p = 0;  // counting sort by dilation (stable)
    for (int d = 1; d <= 6; ++d)
      for (int c = 0; c < C_; ++c)
        if (soffs[c] == d) sd[p++] = c;
    int ni = 0;
    for (int t = 0; t < 4; ++t) {
      int cnt = 0, prev = -1;
      for (int m = 0; m < 16; ++m) {
        const int dd = soffs[sd[t * 16 + m]];
        if (dd != prev && cnt < 6 && ni < MAX_ITEMS) {
          sd[68 + t * 6 + cnt] = dd;
          sd[92 + t * 6 + cnt] = ni++;
          ++cnt;
          prev = dd;
        }
      }
      sd[64 + t] = cnt;
    }
  }
  __syncthreads();
  if (tid < 116) desc[tid] = sd[tid];

  // Pack A-fragments per work item: element layout m=lane&15, k=(lane>>4)*8+j.
  for (int t = 0; t < 4; ++t) {
    const int cnt = sd[64 + t];
    for (int s = 0; s < cnt; ++s) {
      const int dit = sd[68 + t * 6 + s];
      const int wix = sd[92 + t * 6 + s];
      for (int i = tid; i < 1152; i += 256) {  // 2 halves * 9 taps * 64 lanes
        const int h = i / 576;
        const int r2 = i % 576;
        const int tap = r2 >> 6;
        const int lane = r2 & 63;
        const int m = lane & 15, q = lane >> 4;
        const int oc = sd[t * 16 + m];
        const bool act = (soffs[oc] == dit);  // zero-mask other-dilation rows
        unsigned ww[4];
        for (int jj = 0; jj < 4; ++jj) {
          float v0 = 0.f, v1 = 0.f;
          if (act) {
            const int ic0 = h * 32 + q * 8 + jj * 2;
            v0 = w[(oc * C_ + ic0) * 9 + tap];
            v1 = w[(oc * C_ + ic0 + 1) * 9 + tap];
          }
          ww[jj] = bf16rne(v0) | (bf16rne(v1) << 16);
        }
        wpack[(size_t)wix * 1152 + i] = make_uint4(ww[0], ww[1], ww[2], ww[3]);
      }
    }
  }
}

__global__ __launch_bounds__(256, 2) void gsd_conv(
    const float* __restrict__ x, const int* __restrict__ desc,
    const uint4* __restrict__ wpack, float* __restrict__ out) {
  const int tid = threadIdx.x;
  const int gxid = blockIdx.x;
  const int b = gxid >> 5;
  const int yt = (gxid >> 3) & 3;
  const int xt = gxid & 7;
  const int y0 = yt * 32, x0 = xt * 16;

  const int lane = tid & 63;
  const int n = lane & 15;  // MFMA B col / output x
  const int q = lane >> 4;  // MFMA k-group / D row group
  const int wv = tid >> 6;  // wave: output rows wv*8..wv*8+7

  const int slx = tid & 31;   // staging x lane
  const int sicq = tid >> 5;  // staging ic-quad (4 consecutive ic)

  __shared__ unsigned ldsbuf[EY * EX * 16];  // 78848 B -> 2 blocks/CU

  floatx4 acc[4][8];
#pragma unroll
  for (int t = 0; t < 4; ++t)
#pragma unroll
    for (int rr = 0; rr < 8; ++rr) acc[t][rr] = (floatx4){0.f, 0.f, 0.f, 0.f};

  const float* xb = x + (size_t)b * (C_ * HW_ * HW_);
  const int gx = x0 - 6 + slx;
  const int gxc = gx < 0 ? 0 : (gx > 127 ? 127 : gx);
  const bool xin = (unsigned)gx < 128u;
  const bool wr = slx < EX;

  for (int ks = 0; ks < 2; ++ks) {
    // ---- stage 32 input channels (fixed halo 6), fp32->bf16 channel-last ---
    const float* xp = xb + (size_t)(ks * 32 + sicq * 4) * (HW_ * HW_);
#pragma unroll 4
    for (int yy = 0; yy < EY; ++yy) {
      const int gy = y0 - 6 + yy;
      const int gyc = gy < 0 ? 0 : (gy > 127 ? 127 : gy);
      const bool ok = xin & ((unsigned)gy < 128u);
      const float* p = xp + gyc * HW_ + gxc;
      float v0 = p[0];
      float v1 = p[HW_ * HW_];
      float v2 = p[2 * HW_ * HW_];
      float v3 = p[3 * HW_ * HW_];
      if (!ok) { v0 = v1 = v2 = v3 = 0.f; }
      const unsigned lo = bf16rne(v0) | (bf16rne(v1) << 16);
      const unsigned hi = bf16rne(v2) | (bf16rne(v3) << 16);
      if (wr) {
        const int pix = yy * EX + slx;
        const int chunk = (sicq >> 1) ^ ((pix >> 1) & 3);
        const int dws = pix * 16 + chunk * 4 + (sicq & 1) * 2;
        *reinterpret_cast<uint2*>(&ldsbuf[dws]) = make_uint2(lo, hi);
      }
    }
    __syncthreads();

    // ---- compute: 4 octiles x items x 9 taps x 8 rows ----
#pragma unroll
    for (int t = 0; t < 4; ++t) {
      const int cnt = __builtin_amdgcn_readfirstlane(desc[64 + t]);
      for (int s = 0; s < cnt; ++s) {
        const int d = __builtin_amdgcn_readfirstlane(desc[68 + t * 6 + s]);
        const int wix = __builtin_amdgcn_readfirstlane(desc[92 + t * 6 + s]);
        const uint4* wp = wpack + ((size_t)wix * 2 + ks) * 576 + lane;
#pragma unroll
        for (int tap = 0; tap < 9; ++tap) {
          const int ky = tap / 3, kx = tap % 3;
          const short8 af = __builtin_bit_cast(short8, wp[tap * 64]);
          const int pbase =
              (wv * 8 + (ky - 1) * d + 6) * EX + n + (kx - 1) * d + 6;
#pragma unroll
          for (int rr = 0; rr < 8; ++rr) {
            const int pix = pbase + rr * EX;
            const int dws = (pix << 4) + ((q ^ ((pix >> 1) & 3)) << 2);
            const short8 bf =
                *reinterpret_cast<const short8*>(&ldsbuf[dws]);
            acc[t][rr] = __builtin_amdgcn_mfma_f32_16x16x32_bf16(
                af, bf, acc[t][rr], 0, 0, 0);
          }
        }
      }
    }
    if (ks == 0) __syncthreads();  // before restaging overwrites LDS
  }

  // ---- store: all 64 channels real (no padding) ----
  const int ybase = y0 + wv * 8;
#pragma unroll
  for (int t = 0; t < 4; ++t) {
    int cid[4];
#pragma unroll
    for (int reg = 0; reg < 4; ++reg) cid[reg] = desc[t * 16 + q * 4 + reg];
#pragma unroll
    for (int rr = 0; rr < 8; ++rr) {
#pragma unroll
      for (int reg = 0; reg < 4; ++reg) {
        out[((size_t)(b * C_ + cid[reg]) * HW_ + ybase + rr) * HW_ + x0 + n] =
            acc[t][rr][reg];
      }
    }
  }
}

extern "C" void kernel_launch(void* const* d_in, const int* in_sizes, int n_in,
                              void* d_out, int out_size, void* d_ws, size_t ws_size,
                              hipStream_t stream) {
  const float* x = (const float*)d_in[0];    // [16,64,128,128] fp32
  const float* w = (const float*)d_in[1];    // [64,64,3,3] fp32
  const int* offsets = (const int*)d_in[2];  // [64] int32 in [1,6]
  float* out = (float*)d_out;                // [16,64,128,128] fp32

  int* desc = (int*)d_ws;
  uint4* wpack = (uint4*)((char*)d_ws + WS_WPACK_OFF);  // <= 221184 B

  gsd_setup<<<1, 256, 0, stream>>>(offsets, w, desc, wpack);
  gsd_conv<<<dim3(B_ * 4 * 8), 256, 0, stream>>>(x, desc, wpack, out);
}

// Round 4
// 220.612 us; speedup vs baseline: 5.4028x; 1.1067x over previous
//
#include <hip/hip_runtime.h>

// GroupGSDConv round 4: 32x32x16 bf16 MFMA implicit GEMM.
// Block = 512 thr = 8 waves = (octile o in 0..1, row-quad rq in 0..3).
// Spatial tile 16y x 32x, all 64 oc. Channels sorted by dilation; 2 octiles
// of 32 sorted channels; per-octile work items (d-spans, <=6 each), A-frag
// rows of other dilations zero-masked at pack time.
// K=16 per MFMA -> 4 staging passes of 16 ic, LDS buffer 28*44 px * 32 B =
// 39.4 KB -> with launch_bounds(512,4): 2 blocks/CU = 16 waves/CU (4/SIMD).
// One ds_read_b128 feeds a 32x32x16 MFMA (2x FLOP/read vs 16x16x32).
// B reads: 32 consecutive 32B pixels = contiguous 1KB -> conflict-free.

#define HW_ 128
#define C_ 64
#define B_ 16
#define EX 44
#define EY 28
#define MAX_ITEMS 12
#define WS_WPACK_OFF 1024

// desc layout (ints):
//  [0..63]        perm (sorted-by-dilation channel ids)
//  [64+t]         cnt_t   (items in octile t, t<2)
//  [66+t*6+s]     dilation of item (t,s)
//  [78+t*6+s]     wix (wpack index) of item (t,s)
//  [90]           ni_total
//  [91..114]      (octile, d) per wix (setup-internal, used by pack blocks)

typedef __attribute__((ext_vector_type(8))) short short8;
typedef __attribute__((ext_vector_type(16))) float floatx16;

__device__ __forceinline__ unsigned bf16rne(float f) {
  unsigned u = __float_as_uint(f);
  return (u + 0x7FFFu + ((u >> 16) & 1u)) >> 16;  // round-nearest-even
}

__global__ __launch_bounds__(256) void gsd_setup(
    const int* __restrict__ offsets, const float* __restrict__ w,
    int* __restrict__ desc, uint4* __restrict__ wpack) {
  __shared__ int sd[128];
  __shared__ int soffs[C_];
  const int tid = threadIdx.x;
  if (tid < C_) soffs[tid] = offsets[tid];
  __syncthreads();
  if (tid == 0) {
    int p = 0;  // counting sort by dilation (stable)
    for (int d = 1; d <= 6; ++d)
      for (int c = 0; c < C_; ++c)
        if (soffs[c] == d) sd[p++] = c;
    int ni = 0;
    for (int t = 0; t < 2; ++t) {
      int cnt = 0, prev = -1;
      for (int m = 0; m < 32; ++m) {
        const int dd = soffs[sd[t * 32 + m]];
        if (dd != prev && cnt < 6 && ni < MAX_ITEMS) {
          sd[66 + t * 6 + cnt] = dd;
          sd[78 + t * 6 + cnt] = ni;
          sd[91 + ni * 2] = t;
          sd[92 + ni * 2] = dd;
          ++ni;
          ++cnt;
          prev = dd;
        }
      }
      sd[64 + t] = cnt;
    }
    sd[90] = ni;
  }
  __syncthreads();

  const int bid = blockIdx.x;
  if (bid == 0) {
    if (tid < 91) desc[tid] = sd[tid];
    return;
  }
  const int wix = bid - 1;
  if (wix >= sd[90]) return;
  const int o = sd[91 + wix * 2];
  const int dit = sd[92 + wix * 2];

  // Pack A-frags: wpack[wix*2304 + ((ks*9+tap)*64+lane)], element layout
  // m = lane&31, k = (lane>>5)*8 + j, ic = ks*16 + k.
  for (int i = tid; i < 4 * 9 * 64; i += 256) {
    const int ks = i / 576;
    const int r = i % 576;
    const int tap = r >> 6;
    const int lane = r & 63;
    const int m = lane & 31, h = lane >> 5;
    const int oc = sd[o * 32 + m];
    const bool act = (soffs[oc] == dit);  // zero-mask other-dilation rows
    unsigned ww[4];
    for (int jj = 0; jj < 4; ++jj) {
      float v0 = 0.f, v1 = 0.f;
      if (act) {
        const int ic0 = ks * 16 + h * 8 + jj * 2;
        v0 = w[(oc * C_ + ic0) * 9 + tap];
        v1 = w[(oc * C_ + ic0 + 1) * 9 + tap];
      }
      ww[jj] = bf16rne(v0) | (bf16rne(v1) << 16);
    }
    wpack[(size_t)wix * 2304 + i] = make_uint4(ww[0], ww[1], ww[2], ww[3]);
  }
}

__global__ __launch_bounds__(512, 4) void gsd_conv(
    const float* __restrict__ x, const int* __restrict__ desc,
    const uint4* __restrict__ wpack, float* __restrict__ out) {
  const int tid = threadIdx.x;
  const int gxid = blockIdx.x;
  const int b = gxid >> 5;
  const int yt = (gxid >> 2) & 7;
  const int xt = gxid & 3;
  const int y0 = yt * 16, x0 = xt * 32;

  const int lane = tid & 63;
  const int n = lane & 31;   // MFMA B col -> output x
  const int h = lane >> 5;   // k-half
  const int wv = tid >> 6;   // 8 waves
  const int o = wv >> 2;     // octile (32 sorted channels)
  const int rq = wv & 3;     // row-quad: y rows rq*4..rq*4+3

  // staging mapping: 64 x-lanes (44 active), 4 ic-quads, 2-way y split
  const int slx = tid & 63;
  const int sq = (tid >> 6) & 3;
  const int sy2 = tid >> 8;

  __shared__ unsigned ldsbuf[EY * EX * 8];  // 39424 B -> 2 blocks/CU

  floatx16 acc[4];
#pragma unroll
  for (int rt = 0; rt < 4; ++rt)
#pragma unroll
    for (int e = 0; e < 16; ++e) acc[rt][e] = 0.f;

  const float* xb = x + (size_t)b * (C_ * HW_ * HW_);
  const int gx = x0 - 6 + slx;
  const int gxc = gx < 0 ? 0 : (gx > 127 ? 127 : gx);
  const bool xin = ((unsigned)gx < 128u) & (slx < EX);

  const int cnt = __builtin_amdgcn_readfirstlane(desc[64 + o]);

  for (int ks = 0; ks < 4; ++ks) {
    // ---- stage 16 input channels, fp32->bf16, channel-last [pix][16ic] ----
    if (ks) __syncthreads();  // protect buffer from overwrite
    const float* xp = xb + (size_t)(ks * 16 + sq * 4) * (HW_ * HW_);
#pragma unroll 2
    for (int yy = sy2; yy < EY; yy += 2) {
      const int gy = y0 - 6 + yy;
      const int gyc = gy < 0 ? 0 : (gy > 127 ? 127 : gy);
      const bool ok = xin & ((unsigned)gy < 128u);
      const float* p = xp + gyc * HW_ + gxc;
      float v0 = p[0];
      float v1 = p[HW_ * HW_];
      float v2 = p[2 * HW_ * HW_];
      float v3 = p[3 * HW_ * HW_];
      if (!ok) { v0 = v1 = v2 = v3 = 0.f; }
      const unsigned lo = bf16rne(v0) | (bf16rne(v1) << 16);
      const unsigned hi = bf16rne(v2) | (bf16rne(v3) << 16);
      if (slx < EX) {
        const int pix = yy * EX + slx;
        const int dws =
            pix * 8 + (((sq >> 1) ^ (pix & 1)) << 2) + ((sq & 1) << 1);
        *reinterpret_cast<uint2*>(&ldsbuf[dws]) = make_uint2(lo, hi);
      }
    }
    __syncthreads();

    // ---- compute: items of this wave's octile, 9 taps x 4 row-tiles ----
    for (int s = 0; s < cnt; ++s) {
      const int d = __builtin_amdgcn_readfirstlane(desc[66 + o * 6 + s]);
      const int wix = __builtin_amdgcn_readfirstlane(desc[78 + o * 6 + s]);
      const uint4* wp = wpack + ((size_t)wix * 4 + ks) * 576 + lane;
#pragma unroll
      for (int tap = 0; tap < 9; ++tap) {
        const int ky = tap / 3 - 1, kx = tap % 3 - 1;
        const short8 af = __builtin_bit_cast(short8, wp[tap * 64]);
        const int pybase = rq * 4 + ky * d + 6;
        const int pxb = n + kx * d + 6;
#pragma unroll
        for (int rt = 0; rt < 4; ++rt) {
          const int pix = (pybase + rt) * EX + pxb;
          const int dws = (pix << 3) + ((h ^ (pix & 1)) << 2);
          const short8 bf = *reinterpret_cast<const short8*>(&ldsbuf[dws]);
          acc[rt] = __builtin_amdgcn_mfma_f32_32x32x16_bf16(af, bf, acc[rt],
                                                            0, 0, 0);
        }
      }
    }
  }

  // ---- store: D col=lane&31 -> x, row=(reg&3)+8*(reg>>2)+4*h -> oc ----
  int oc[16];
#pragma unroll
  for (int reg = 0; reg < 16; ++reg) {
    const int row = (reg & 3) + 8 * (reg >> 2) + 4 * h;
    oc[reg] = desc[o * 32 + row];
  }
#pragma unroll
  for (int rt = 0; rt < 4; ++rt) {
    const int y = y0 + rq * 4 + rt;
#pragma unroll
    for (int reg = 0; reg < 16; ++reg) {
      out[((size_t)(b * C_ + oc[reg]) * HW_ + y) * HW_ + x0 + n] =
          acc[rt][reg];
    }
  }
}

extern "C" void kernel_launch(void* const* d_in, const int* in_sizes, int n_in,
                              void* d_out, int out_size, void* d_ws, size_t ws_size,
                              hipStream_t stream) {
  const float* x = (const float*)d_in[0];    // [16,64,128,128] fp32
  const float* w = (const float*)d_in[1];    // [64,64,3,3] fp32
  const int* offsets = (const int*)d_in[2];  // [64] int32 in [1,6]
  float* out = (float*)d_out;                // [16,64,128,128] fp32

  int* desc = (int*)d_ws;
  uint4* wpack = (uint4*)((char*)d_ws + WS_WPACK_OFF);  // <= 442368 B

  gsd_setup<<<dim3(1 + MAX_ITEMS), 256, 0, stream>>>(offsets, w, desc, wpack);
  gsd_conv<<<dim3(B_ * 8 * 4), 512, 0, stream>>>(x, desc, wpack, out);
}